// Round 7
// baseline (479.375 us; speedup 1.0000x reference)
//
#include <hip/hip_runtime.h>
#include <stdint.h>

// Problem constants (B=2, S=2048, D=2048, H=16, HD=128)
#define S_LEN 2048
#define DMODEL 2048
#define NHEAD 16
#define HDIM 128

typedef __attribute__((ext_vector_type(8))) short short8;   // 8 bf16 (4 VGPRs)
typedef __attribute__((ext_vector_type(4))) float floatx4;  // MFMA acc

__device__ __forceinline__ unsigned short f2b(float f) {
  union { float f; unsigned u; } v; v.f = f;
  unsigned r = v.u + 0x7FFFu + ((v.u >> 16) & 1u);  // RNE
  return (unsigned short)(r >> 16);
}

// async global->LDS, 16B per lane; LDS dest is wave-uniform base + lane*16
__device__ __forceinline__ void load_lds16(const unsigned short* g, unsigned short* l) {
  __builtin_amdgcn_global_load_lds((const __attribute__((address_space(1))) void*)g,
                                   (__attribute__((address_space(3))) void*)l, 16, 0, 0);
}

// ---------------- fused fp32 -> bf16 conversion (x in 2 slices + 4 weights) ----------------
__global__ __launch_bounds__(256) void cvt_all(const float* __restrict__ x,
                                               const float* __restrict__ Wq, const float* __restrict__ Wk,
                                               const float* __restrict__ Wv, const float* __restrict__ Wo,
                                               unsigned short* __restrict__ xb,
                                               unsigned short* __restrict__ Wqb, unsigned short* __restrict__ Wkb,
                                               unsigned short* __restrict__ Wvb, unsigned short* __restrict__ Wob) {
  const size_t idx = (size_t)blockIdx.x * 256 + threadIdx.x;  // < 2^20 per slice
  const int y = blockIdx.y;
  const float4* s; ushort4* d;
  if (y == 0)      { s = (const float4*)x;               d = (ushort4*)xb; }
  else if (y == 1) { s = (const float4*)x + (1u << 20);  d = (ushort4*)xb + (1u << 20); }
  else if (y == 2) { s = (const float4*)Wq;              d = (ushort4*)Wqb; }
  else if (y == 3) { s = (const float4*)Wk;              d = (ushort4*)Wkb; }
  else if (y == 4) { s = (const float4*)Wv;              d = (ushort4*)Wvb; }
  else             { s = (const float4*)Wo;              d = (ushort4*)Wob; }
  float4 f = s[idx];
  ushort4 o;
  o.x = f2b(f.x); o.y = f2b(f.y); o.z = f2b(f.z); o.w = f2b(f.w);
  d[idx] = o;
}

// ---------------- 256x256 8-phase GEMM, register-double-buffered ----------------
// C = A @ Bw^T + bias. A:[M,K] bf16, Bw:[N,K] bf16 (weight row = C col). K = 2048.
// 512 threads = 8 waves (wm 0..1 x wn 0..3); per-wave C tile = 128x64 -> acc[8][4].
// LDS: [buf2][op2(A,B)][ks2][256 rows][32 k] bf16 = 128 KB (layout identical to the
// proven round-4 kernel: slot = logical ^ ((row>>1)&3), 0 bank conflicts measured).
//
// DELTA vs round 4 (measured: phases serialize LDS-read-burst -> barrier -> MFMA;
// odd phases ~940cy LDS + 516cy MFMA back-to-back): REGISTER DOUBLE BUFFER.
// Each phase: BAR; STAGE(p); issue ds_reads for phase p+1 into the ALTERNATE av/bv
// register set; MFMA(p) on registers loaded during phase p-1. No explicit lgkmcnt:
// the compiler emits counted waits for the current operands (drained long ago), so
// the new reads retire in the LDS pipe UNDER the MFMA cluster. One barrier/phase.
// vmcnt(4) at the END of every even phase: drains the two regions staged 2-3 phases
// earlier; every early-read of a region happens >=1 barrier after its drain-vmcnt
// (cross-wave safe); every stage overwrites a region whose last consuming MFMA is
// >=2 barriers prior. 4-8 loads always in flight (never drained to 0 in-loop).
// MODE 0: bf16 row-major [M,2048]; MODE 1: bf16 V^T [(b*D+col)*S + s]; MODE 2: fp32 row-major.

#define REG256(buf, op, ks) (lds + ((((buf)*2 + (op)) * 2 + (ks)) * 8192))
#define STAGE256(buf, op, ks, kt)                                                    \
  do {                                                                               \
    unsigned short* _d = REG256(buf, op, ks);                                        \
    const unsigned short* _g0 = ((op) ? gB[0] : gA[0]) + (kt) * 64 + (ks) * 32;      \
    const unsigned short* _g1 = ((op) ? gB[1] : gA[1]) + (kt) * 64 + (ks) * 32;      \
    load_lds16(_g0, _d + ldso[0]);                                                   \
    load_lds16(_g1, _d + ldso[1]);                                                   \
  } while (0)
#define RDA_TO(dst, buf, ks)                                                         \
  { _Pragma("unroll") for (int mf = 0; mf < 8; mf++)                                 \
      dst[mf] = *(const short8*)(REG256(buf, 0, ks) + aoff + mf * 512); }
#define RDB_TO(dst, buf, ks, nh)                                                     \
  { dst[0] = *(const short8*)(REG256(buf, 1, ks) + boff + (nh) * 1024);              \
    dst[1] = *(const short8*)(REG256(buf, 1, ks) + boff + (nh) * 1024 + 512); }
#define MFMA16(a, b, nh)                                                             \
  { __builtin_amdgcn_s_setprio(1);                                                   \
    _Pragma("unroll") for (int mf = 0; mf < 8; mf++) {                               \
      acc[mf][(nh)*2]   = __builtin_amdgcn_mfma_f32_16x16x32_bf16(a[mf], b[0], acc[mf][(nh)*2],   0, 0, 0); \
      acc[mf][(nh)*2+1] = __builtin_amdgcn_mfma_f32_16x16x32_bf16(a[mf], b[1], acc[mf][(nh)*2+1], 0, 0, 0); } \
    __builtin_amdgcn_s_setprio(0); }
#define BAR256 __builtin_amdgcn_s_barrier()
#define VMC4 asm volatile("s_waitcnt vmcnt(4)" ::: "memory")
#define VMC0 asm volatile("s_waitcnt vmcnt(0)" ::: "memory")

__device__ __forceinline__ void gemm256_body(const unsigned short* __restrict__ A,
                                             const unsigned short* __restrict__ Bw,
                                             const float* __restrict__ bias,
                                             void* __restrict__ out, int mode, float scale,
                                             int m0, int n0, unsigned short* lds) {
  const int K = DMODEL;
  const int t = threadIdx.x;
  const int lane = t & 63, w = t >> 6;
  const int quad = lane >> 4, lc = lane & 15;
  const int wm = w >> 2, wn = w & 3;

  // staging geometry: wave chunk c = w*2+i covers rows c*16 + (lane>>2); lane stores
  // slot lane&3, fetching logical k-chunk (lane&3)^((lane>>3)&3) (XOR pre-swizzle).
  const int chunkoff = ((lane & 3) ^ ((lane >> 3) & 3)) * 8;
  const unsigned short* gA[2];
  const unsigned short* gB[2];
  int ldso[2];
#pragma unroll
  for (int i = 0; i < 2; i++) {
    const int c = w * 2 + i;
    const int r = c * 16 + (lane >> 2);
    gA[i] = A + (size_t)(m0 + r) * K + chunkoff;
    gB[i] = Bw + (size_t)(n0 + r) * K + chunkoff;
    ldso[i] = c * 512 + lane * 8;
  }

  // fragment read offsets: row*32 ushorts + (quad ^ ((lc>>1)&3))*8
  const int rsw = ((lc >> 1) & 3);
  const int aoff = (wm * 128 + lc) * 32 + ((quad ^ rsw) * 8);
  const int boff = (wn * 64 + lc) * 32 + ((quad ^ rsw) * 8);

  floatx4 acc[8][4] = {};
  short8 av0[8], av1[8], bv0[2], bv1[2];   // double-buffered operand sets

  // prologue: stage T0 (4 regions) + T1.ks0 (2 regions) = 12 loads; vmcnt(4) leaves
  // exactly {T1.A.ks0, T1.B.ks0} outstanding = the steady-state ph7/ph8 leftover.
  STAGE256(0, 0, 0, 0); STAGE256(0, 1, 0, 0); STAGE256(0, 0, 1, 0); STAGE256(0, 1, 1, 0);
  STAGE256(1, 0, 0, 1); STAGE256(1, 1, 0, 1);
  VMC4;
  BAR256;
  // preload C1 operands (buf0.ks0, nh0)
  RDA_TO(av0, 0, 0);
  RDB_TO(bv0, 0, 0, 0);

  const int NKT = K / 64;      // 32
  const int NIT = NKT / 2;     // 16
  for (int it = 0; it < NIT; it++) {
    const int kt1 = 2 * it + 1;
    const int kt2 = (2 * it + 2 < NKT) ? 2 * it + 2 : NKT - 1;  // clamped: dummy stages
    const int kt3 = (2 * it + 3 < NKT) ? 2 * it + 3 : NKT - 1;  // keep vmcnt uniform
    // ph1: C(buf0.ks0,nh0) on [av0,bv0] | read bv1 <- buf0.ks0 nh1 | stage buf1.A.ks1
    BAR256;
    STAGE256(1, 0, 1, kt1);
    RDB_TO(bv1, 0, 0, 1);
    MFMA16(av0, bv0, 0);
    // ph2: C(buf0.ks0,nh1) on [av0,bv1] | read av1,bv0 <- buf0.ks1 | stage buf1.B.ks1
    BAR256;
    STAGE256(1, 1, 1, kt1);
    RDA_TO(av1, 0, 1);
    RDB_TO(bv0, 0, 1, 0);
    MFMA16(av0, bv1, 1);
    VMC4;   // drains prev ph7/ph8 regions (buf1.ks0) -> early-read at ph4 is safe
    // ph3: C(buf0.ks1,nh0) on [av1,bv0] | read bv1 <- buf0.ks1 nh1 | stage buf0.A.ks0
    BAR256;
    STAGE256(0, 0, 0, kt2);
    RDB_TO(bv1, 0, 1, 1);
    MFMA16(av1, bv0, 0);
    // ph4: C(buf0.ks1,nh1) on [av1,bv1] | read av0,bv0 <- buf1.ks0 | stage buf0.B.ks0
    BAR256;
    STAGE256(0, 1, 0, kt2);
    RDA_TO(av0, 1, 0);
    RDB_TO(bv0, 1, 0, 0);
    MFMA16(av1, bv1, 1);
    VMC4;   // drains ph1/ph2 regions (buf1.ks1) -> early-read at ph6 is safe
    // ph5: C(buf1.ks0,nh0) on [av0,bv0] | read bv1 <- buf1.ks0 nh1 | stage buf0.A.ks1
    BAR256;
    STAGE256(0, 0, 1, kt2);
    RDB_TO(bv1, 1, 0, 1);
    MFMA16(av0, bv0, 0);
    // ph6: C(buf1.ks0,nh1) on [av0,bv1] | read av1,bv0 <- buf1.ks1 | stage buf0.B.ks1
    BAR256;
    STAGE256(0, 1, 1, kt2);
    RDA_TO(av1, 1, 1);
    RDB_TO(bv0, 1, 1, 0);
    MFMA16(av0, bv1, 1);
    VMC4;   // drains ph3/ph4 regions (buf0.ks0) -> early-read at ph8 is safe
    // ph7: C(buf1.ks1,nh0) on [av1,bv0] | read bv1 <- buf1.ks1 nh1 | stage buf1.A.ks0
    BAR256;
    STAGE256(1, 0, 0, kt3);
    RDB_TO(bv1, 1, 1, 1);
    MFMA16(av1, bv0, 0);
    // ph8: C(buf1.ks1,nh1) on [av1,bv1] | read av0,bv0 <- buf0.ks0 | stage buf1.B.ks0
    BAR256;
    STAGE256(1, 1, 0, kt3);
    RDA_TO(av0, 0, 0);
    RDB_TO(bv0, 0, 0, 0);
    MFMA16(av1, bv1, 1);
    VMC4;   // drains ph5/ph6 regions (buf0.ks1) -> early-read at next ph2 is safe
  }

  // drain all outstanding async LDS writes before epilogue / endpgm
  VMC0;
  BAR256;

  // epilogue: C/D frag row = quad*4 + r (A side), col = lc (B side)
#pragma unroll
  for (int nf = 0; nf < 4; nf++) {
    const int col = n0 + wn * 64 + nf * 16 + lc;
    const float bcol = bias[col];
#pragma unroll
    for (int mf = 0; mf < 8; mf++) {
      const int row0 = m0 + wm * 128 + mf * 16 + quad * 4;
      if (mode == 1) {
        ushort4 o;
        o.x = f2b((acc[mf][nf][0] + bcol) * scale);
        o.y = f2b((acc[mf][nf][1] + bcol) * scale);
        o.z = f2b((acc[mf][nf][2] + bcol) * scale);
        o.w = f2b((acc[mf][nf][3] + bcol) * scale);
        const int b = row0 >> 11;          // row0 / S_LEN
        const int s = row0 & (S_LEN - 1);
        *(ushort4*)&((unsigned short*)out)[((size_t)(b * DMODEL + col)) * S_LEN + s] = o;
      } else if (mode == 2) {
#pragma unroll
        for (int r = 0; r < 4; r++)
          ((float*)out)[(size_t)(row0 + r) * DMODEL + col] = (acc[mf][nf][r] + bcol) * scale;
      } else {
#pragma unroll
        for (int r = 0; r < 4; r++)
          ((unsigned short*)out)[(size_t)(row0 + r) * DMODEL + col] = f2b((acc[mf][nf][r] + bcol) * scale);
      }
    }
  }
}

// fused QKV: grid (24, 16) natural order (XCD swizzle reverted: measured FETCH 94->176 MB).
// col-tiles 0-7 -> Q, 8-15 -> K, 16-23 -> V (V^T epilogue)
__global__ __launch_bounds__(512, 2)
void qkv256(const unsigned short* __restrict__ xb,
            const unsigned short* __restrict__ Wqb, const unsigned short* __restrict__ Wkb,
            const unsigned short* __restrict__ Wvb,
            const float* __restrict__ bq, const float* __restrict__ bk, const float* __restrict__ bvp,
            unsigned short* __restrict__ Qb, unsigned short* __restrict__ Kb,
            unsigned short* __restrict__ Vtb, float qscale) {
  __shared__ unsigned short lds[65536];  // 128 KB
  const int sel = blockIdx.x >> 3;
  const int n0 = (blockIdx.x & 7) * 256;
  const int m0 = blockIdx.y * 256;
  const unsigned short* Bw = (sel == 0) ? Wqb : (sel == 1) ? Wkb : Wvb;
  const float* bias = (sel == 0) ? bq : (sel == 1) ? bk : bvp;
  void* out = (sel == 0) ? (void*)Qb : (sel == 1) ? (void*)Kb : (void*)Vtb;
  const float scale = (sel == 0) ? qscale : 1.f;
  const int mode = (sel == 2) ? 1 : 0;
  gemm256_body(xb, Bw, bias, out, mode, scale, m0, n0, lds);
}

// output projection: grid (8, 16), fp32 out
__global__ __launch_bounds__(512, 2)
void out256(const unsigned short* __restrict__ Ob, const unsigned short* __restrict__ Wob,
            const float* __restrict__ bo, float* __restrict__ out) {
  __shared__ unsigned short lds[65536];
  gemm256_body(Ob, Wob, bo, out, 2, 1.f, blockIdx.y * 256, blockIdx.x * 256, lds);
}

// ---------------- Flash attention (causal), BM=128, S^T orientation ----------------
// Q,K: [b,s,h,hd] rows of [B*S, D]; Vt: [b,h,hd,s]; O: [b,s,h,hd].
// Q pre-scaled by log2(e)/sqrt(HD) so softmax uses exp2.
__global__ __launch_bounds__(256, 2)
void attn_fwd(const unsigned short* __restrict__ Qg, const unsigned short* __restrict__ Kg,
              const unsigned short* __restrict__ Vtg, unsigned short* __restrict__ Og) {
  __shared__ unsigned short Ks[2][64 * 128];  // 32 KB [buf][krow][chunk^(krow&15)]
  __shared__ unsigned short Vs[128 * 64];     // 16 KB [hd][chunk^(hd&7)]
  __shared__ unsigned short Ps[128 * 72];     // 18 KB [query][key], pitch 72 spreads banks

  const int t = threadIdx.x;
  const int lane = t & 63, w = t >> 6;
  const int quad = lane >> 4, lc = lane & 15;
  const int y = blockIdx.y;
  const int tile = (y < 16) ? (int)blockIdx.x : 15 - (int)blockIdx.x;
  const int b = y >> 4, h = y & 15;
  const size_t qkbase = (size_t)b * S_LEN * DMODEL + h * HDIM;
  const size_t vtbase = ((size_t)(b * DMODEL + h * HDIM)) * S_LEN;
  const int q0 = tile * 128;
  const int wrow = q0 + w * 32;  // wave's first q-row

  short8 aq[2][4];
#pragma unroll
  for (int pm = 0; pm < 2; pm++)
#pragma unroll
    for (int ks = 0; ks < 4; ks++)
      aq[pm][ks] = *(const short8*)&Qg[qkbase + (size_t)(wrow + pm * 16 + lc) * DMODEL + ks * 32 + quad * 8];

  const unsigned short* kga[4];
  const unsigned short* vga[4];
  int kloff[4], vloff[4];
#pragma unroll
  for (int i = 0; i < 4; i++) {
    int c = w * 4 + i;
    int krow = 4 * c + (lane >> 4);
    kga[i] = Kg + qkbase + (size_t)krow * DMODEL + ((lane & 15) ^ (krow & 15)) * 8;
    kloff[i] = c * 512 + lane * 8;
    int vrow = 8 * c + (lane >> 3);
    vga[i] = Vtg + vtbase + (size_t)vrow * S_LEN + ((lane & 7) ^ (vrow & 7)) * 8;
    vloff[i] = c * 512 + lane * 8;
  }

  floatx4 oaccT[8][2] = {};
  float m_run[2] = {-1e30f, -1e30f}, l_run[2] = {0.f, 0.f};

  const int kiters = 2 * tile + 2;

#pragma unroll
  for (int i = 0; i < 4; i++) load_lds16(kga[i], &Ks[0][kloff[i]]);

  for (int kb = 0; kb < kiters; kb++) {
    const int k0 = kb * 64;
    const int cur = kb & 1;
    __syncthreads();

#pragma unroll
    for (int i = 0; i < 4; i++) load_lds16(vga[i] + k0, &Vs[vloff[i]]);
    {
      const size_t knext = (size_t)((kb + 1 < kiters) ? k0 + 64 : k0) * DMODEL;
#pragma unroll
      for (int i = 0; i < 4; i++) load_lds16(kga[i] + knext, &Ks[cur ^ 1][kloff[i]]);
    }

    const bool hasw = (k0 <= wrow + 31);
    float alpha[2];
    if (hasw) {
      floatx4 st[4][2];
#pragma unroll
      for (int mt = 0; mt < 4; mt++)
#pragma unroll
        for (int pm = 0; pm < 2; pm++) st[mt][pm] = (floatx4){0.f, 0.f, 0.f, 0.f};
      __builtin_amdgcn_s_setprio(1);
#pragma unroll
      for (int ks = 0; ks < 4; ks++) {
        short8 kf[4];
#pragma unroll
        for (int mt = 0; mt < 4; mt++) {
          int n = mt * 16 + lc;
          kf[mt] = *(const short8*)&Ks[cur][n * 128 + (((ks * 4 + quad) ^ (n & 15)) * 8)];
        }
#pragma unroll
        for (int mt = 0; mt < 4; mt++)
#pragma unroll
          for (int pm = 0; pm < 2; pm++)
            st[mt][pm] = __builtin_amdgcn_mfma_f32_16x16x32_bf16(kf[mt], aq[pm][ks], st[mt][pm], 0, 0, 0);
      }
      __builtin_amdgcn_s_setprio(0);

      float mx[2] = {-1e30f, -1e30f};
      if (k0 + 63 > wrow) {
#pragma unroll
        for (int pm = 0; pm < 2; pm++) {
          const int qq = wrow + pm * 16 + lc;
#pragma unroll
          for (int mt = 0; mt < 4; mt++) {
            const int key = k0 + mt * 16 + quad * 4;
#pragma unroll
            for (int r = 0; r < 4; r++) {
              if (key + r > qq) st[mt][pm][r] = -1e30f;
              mx[pm] = fmaxf(mx[pm], st[mt][pm][r]);
            }
          }
        }
      } else {
#pragma unroll
        for (int pm = 0; pm < 2; pm++)
#pragma unroll
          for (int mt = 0; mt < 4; mt++)
#pragma unroll
            for (int r = 0; r < 4; r++) mx[pm] = fmaxf(mx[pm], st[mt][pm][r]);
      }
#pragma unroll
      for (int pm = 0; pm < 2; pm++) {
        mx[pm] = fmaxf(mx[pm], __shfl_xor(mx[pm], 16));
        mx[pm] = fmaxf(mx[pm], __shfl_xor(mx[pm], 32));
        float mnew = fmaxf(m_run[pm], mx[pm]);
        alpha[pm] = __builtin_amdgcn_exp2f(m_run[pm] - mnew);
        m_run[pm] = mnew;
        l_run[pm] *= alpha[pm];
      }

#pragma unroll
      for (int pm = 0; pm < 2; pm++)
#pragma unroll
        for (int mt = 0; mt < 4; mt++) {
          float p0 = __builtin_amdgcn_exp2f(st[mt][pm][0] - m_run[pm]);
          float p1 = __builtin_amdgcn_exp2f(st[mt][pm][1] - m_run[pm]);
          float p2 = __builtin_amdgcn_exp2f(st[mt][pm][2] - m_run[pm]);
          float p3 = __builtin_amdgcn_exp2f(st[mt][pm][3] - m_run[pm]);
          l_run[pm] += (p0 + p1) + (p2 + p3);
          ushort4 o;
          o.x = f2b(p0); o.y = f2b(p1); o.z = f2b(p2); o.w = f2b(p3);
          *(ushort4*)&Ps[(w * 32 + pm * 16 + lc) * 72 + mt * 16 + quad * 4] = o;
        }
    }

    asm volatile("s_waitcnt vmcnt(4)\n\ts_barrier" ::: "memory");

    if (hasw) {
#pragma unroll
      for (int mt8 = 0; mt8 < 8; mt8++)
#pragma unroll
        for (int pm = 0; pm < 2; pm++) {
          oaccT[mt8][pm][0] *= alpha[pm]; oaccT[mt8][pm][1] *= alpha[pm];
          oaccT[mt8][pm][2] *= alpha[pm]; oaccT[mt8][pm][3] *= alpha[pm];
        }

#pragma unroll
      for (int ks = 0; ks < 2; ks++) {
        short8 pf[2];
#pragma unroll
        for (int pm = 0; pm < 2; pm++)
          pf[pm] = *(const short8*)&Ps[(w * 32 + pm * 16 + lc) * 72 + ks * 32 + quad * 8];
        __builtin_amdgcn_s_setprio(1);
#pragma unroll
        for (int mt8 = 0; mt8 < 8; mt8++) {
          int n = mt8 * 16 + lc;
          short8 vf = *(const short8*)&Vs[n * 64 + (((ks * 4 + quad) ^ (n & 7)) * 8)];
#pragma unroll
          for (int pm = 0; pm < 2; pm++)
            oaccT[mt8][pm] = __builtin_amdgcn_mfma_f32_16x16x32_bf16(vf, pf[pm], oaccT[mt8][pm], 0, 0, 0);
        }
        __builtin_amdgcn_s_setprio(0);
      }
    }
  }

#pragma unroll
  for (int pm = 0; pm < 2; pm++) {
    l_run[pm] += __shfl_xor(l_run[pm], 16);
    l_run[pm] += __shfl_xor(l_run[pm], 32);
    float inv = 1.f / l_run[pm];
    size_t obase = ((size_t)(b * S_LEN + wrow + pm * 16 + lc)) * DMODEL + h * HDIM;
#pragma unroll
    for (int mt8 = 0; mt8 < 8; mt8++) {
      ushort4 o;
      o.x = f2b(oaccT[mt8][pm][0] * inv);
      o.y = f2b(oaccT[mt8][pm][1] * inv);
      o.z = f2b(oaccT[mt8][pm][2] * inv);
      o.w = f2b(oaccT[mt8][pm][3] * inv);
      *(ushort4*)&Og[obase + mt8 * 16 + quad * 4] = o;
    }
  }
}

// ---------------- launch ----------------
extern "C" void kernel_launch(void* const* d_in, const int* in_sizes, int n_in,
                              void* d_out, int out_size, void* d_ws, size_t ws_size,
                              hipStream_t stream) {
  const float* x  = (const float*)d_in[0];
  const float* Wq = (const float*)d_in[1];
  const float* bq = (const float*)d_in[2];
  const float* Wk = (const float*)d_in[3];
  const float* bk = (const float*)d_in[4];
  const float* Wv = (const float*)d_in[5];
  const float* bv = (const float*)d_in[6];
  const float* Wo = (const float*)d_in[7];
  const float* bo = (const float*)d_in[8];

  char* w = (char*)d_ws;  // needs 112 MB
  unsigned short* xb  = (unsigned short*)(w);
  unsigned short* Wqb = (unsigned short*)(w + (size_t)16 * (1 << 20));
  unsigned short* Wkb = (unsigned short*)(w + (size_t)24 * (1 << 20));
  unsigned short* Wvb = (unsigned short*)(w + (size_t)32 * (1 << 20));
  unsigned short* Wob = (unsigned short*)(w + (size_t)40 * (1 << 20));
  unsigned short* Qb  = (unsigned short*)(w + (size_t)48 * (1 << 20));
  unsigned short* Kb  = (unsigned short*)(w + (size_t)64 * (1 << 20));
  unsigned short* Vtb = (unsigned short*)(w + (size_t)80 * (1 << 20));
  unsigned short* Ob  = (unsigned short*)(w + (size_t)96 * (1 << 20));

  cvt_all<<<dim3(4096, 6), 256, 0, stream>>>(x, Wq, Wk, Wv, Wo, xb, Wqb, Wkb, Wvb, Wob);

  // Q scale: log2(e)/sqrt(128) so attention softmax can use exp2 directly
  const float qscale = 0.08838834764831843f * 1.4426950408889634f;
  qkv256<<<dim3(24, 16), 512, 0, stream>>>(xb, Wqb, Wkb, Wvb, bq, bk, bv, Qb, Kb, Vtb, qscale);

  attn_fwd<<<dim3(16, 32), 256, 0, stream>>>(Qb, Kb, Vtb, Ob);

  out256<<<dim3(8, 16), 512, 0, stream>>>(Ob, Wob, bo, (float*)d_out);
}

// Round 8
// 367.457 us; speedup vs baseline: 1.3046x; 1.3046x over previous
//
#include <hip/hip_runtime.h>
#include <stdint.h>

// Problem constants (B=2, S=2048, D=2048, H=16, HD=128)
#define S_LEN 2048
#define DMODEL 2048
#define NHEAD 16
#define HDIM 128

typedef __attribute__((ext_vector_type(8))) short short8;   // 8 bf16 (4 VGPRs)
typedef __attribute__((ext_vector_type(4))) float floatx4;  // MFMA acc

__device__ __forceinline__ unsigned short f2b(float f) {
  union { float f; unsigned u; } v; v.f = f;
  unsigned r = v.u + 0x7FFFu + ((v.u >> 16) & 1u);  // RNE
  return (unsigned short)(r >> 16);
}

// async global->LDS, 16B per lane; LDS dest is wave-uniform base + lane*16
__device__ __forceinline__ void load_lds16(const unsigned short* g, unsigned short* l) {
  __builtin_amdgcn_global_load_lds((const __attribute__((address_space(1))) void*)g,
                                   (__attribute__((address_space(3))) void*)l, 16, 0, 0);
}

// ---------------- fused fp32 -> bf16 conversion (x in 2 slices + 4 weights) ----------------
__global__ __launch_bounds__(256) void cvt_all(const float* __restrict__ x,
                                               const float* __restrict__ Wq, const float* __restrict__ Wk,
                                               const float* __restrict__ Wv, const float* __restrict__ Wo,
                                               unsigned short* __restrict__ xb,
                                               unsigned short* __restrict__ Wqb, unsigned short* __restrict__ Wkb,
                                               unsigned short* __restrict__ Wvb, unsigned short* __restrict__ Wob) {
  const size_t idx = (size_t)blockIdx.x * 256 + threadIdx.x;  // < 2^20 per slice
  const int y = blockIdx.y;
  const float4* s; ushort4* d;
  if (y == 0)      { s = (const float4*)x;               d = (ushort4*)xb; }
  else if (y == 1) { s = (const float4*)x + (1u << 20);  d = (ushort4*)xb + (1u << 20); }
  else if (y == 2) { s = (const float4*)Wq;              d = (ushort4*)Wqb; }
  else if (y == 3) { s = (const float4*)Wk;              d = (ushort4*)Wkb; }
  else if (y == 4) { s = (const float4*)Wv;              d = (ushort4*)Wvb; }
  else             { s = (const float4*)Wo;              d = (ushort4*)Wob; }
  float4 f = s[idx];
  ushort4 o;
  o.x = f2b(f.x); o.y = f2b(f.y); o.z = f2b(f.z); o.w = f2b(f.w);
  d[idx] = o;
}

// ---------------- GEMM body: C = A @ Bw^T + bias, A:[M,K] bf16, Bw:[N,K] bf16 ----------------
// Round-0 proven body (best measured end-to-end). m97-style: global_load_lds width=16
// staging into unpadded [128][64] LDS tiles with XOR k-chunk swizzle
// (LDS[row][slot] = G[row][slot ^ (row&7)]) for bank spread.
// MODE 0: bf16 row-major out [M,N];  MODE 1: bf16 V-transposed out [(b*D+col)*S + s];
// MODE 2: fp32 row-major out.
template <int MODE>
__device__ __forceinline__ void gemm128_body(const unsigned short* __restrict__ A,
                                             const unsigned short* __restrict__ Bw,
                                             const float* __restrict__ bias,
                                             void* __restrict__ Cout,
                                             int M, int N, int K, float scale,
                                             int m0, int n0,
                                             unsigned short* As, unsigned short* Bs) {
  const int t = threadIdx.x;
  const int lane = t & 63, wave = t >> 6;
  const int quad = lane >> 4, lc = lane & 15;
  const int wm = wave >> 1, wn = wave & 1;  // 2x2 waves, 64x64 per wave

  // staging geometry: chunk c = wave*4+i covers rows c*8..c*8+8; lane covers
  // row c*8+(lane>>3), global k-chunk ((lane&7) ^ (lane>>3)) (XOR swizzle)
  const int srow = lane >> 3;
  const int skoff = ((lane & 7) ^ srow) * 8;
  const unsigned short* Ag[4];
  const unsigned short* Bg[4];
  unsigned short* Al[4];
  unsigned short* Bl[4];
#pragma unroll
  for (int i = 0; i < 4; i++) {
    int c = wave * 4 + i;
    Ag[i] = A + (size_t)(m0 + c * 8 + srow) * K + skoff;
    Bg[i] = Bw + (size_t)(n0 + c * 8 + srow) * K + skoff;
    Al[i] = &As[c * 512 + lane * 8];
    Bl[i] = &Bs[c * 512 + lane * 8];
  }

  // fragment-read swizzled k offsets (elements): want global chunk ks*4+quad at row r
  // -> LDS slot (ks*4+quad) ^ (r&7); our rows have r&7 == lc&7
  int koff[2];
#pragma unroll
  for (int ks = 0; ks < 2; ks++) koff[ks] = ((ks * 4 + quad) ^ (lc & 7)) * 8;

  floatx4 acc[4][4] = {};

  for (int kt = 0; kt < K; kt += 64) {
    if (kt) __syncthreads();  // protect LDS from overwrite while prior reads in flight
#pragma unroll
    for (int i = 0; i < 4; i++) {
      load_lds16(Ag[i] + kt, Al[i]);
      load_lds16(Bg[i] + kt, Bl[i]);
    }
    __syncthreads();  // drains vmcnt(0): staged tile visible
#pragma unroll
    for (int ks = 0; ks < 2; ks++) {
      short8 av[4], bv[4];
#pragma unroll
      for (int mt = 0; mt < 4; mt++)
        av[mt] = *(const short8*)&As[(wm * 64 + mt * 16 + lc) * 64 + koff[ks]];
#pragma unroll
      for (int nt = 0; nt < 4; nt++)
        bv[nt] = *(const short8*)&Bs[(wn * 64 + nt * 16 + lc) * 64 + koff[ks]];
#pragma unroll
      for (int mt = 0; mt < 4; mt++)
#pragma unroll
        for (int nt = 0; nt < 4; nt++)
          acc[mt][nt] = __builtin_amdgcn_mfma_f32_16x16x32_bf16(av[mt], bv[nt], acc[mt][nt], 0, 0, 0);
    }
  }

#pragma unroll
  for (int nt = 0; nt < 4; nt++) {
    const int col = n0 + wn * 64 + nt * 16 + lc;
    const float bcol = bias[col];
#pragma unroll
    for (int mt = 0; mt < 4; mt++) {
      const int row0 = m0 + wm * 64 + mt * 16 + quad * 4;
      if (MODE == 1) {
        // V^T layout: out[(b*D + col)*S + s], 4 consecutive s per lane -> one 8B store
        ushort4 o;
        o.x = f2b((acc[mt][nt][0] + bcol) * scale);
        o.y = f2b((acc[mt][nt][1] + bcol) * scale);
        o.z = f2b((acc[mt][nt][2] + bcol) * scale);
        o.w = f2b((acc[mt][nt][3] + bcol) * scale);
        int b = row0 >> 11;            // row0 / S_LEN
        int s = row0 & (S_LEN - 1);
        *(ushort4*)&((unsigned short*)Cout)[((size_t)(b * DMODEL + col)) * S_LEN + s] = o;
      } else {
#pragma unroll
        for (int r = 0; r < 4; r++) {
          float v = (acc[mt][nt][r] + bcol) * scale;
          if (MODE == 2)
            ((float*)Cout)[(size_t)(row0 + r) * N + col] = v;
          else
            ((unsigned short*)Cout)[(size_t)(row0 + r) * N + col] = f2b(v);
        }
      }
    }
  }
}

// fused QKV projections: grid (48, 32). x 0-15 -> Q (scaled), 16-31 -> K, 32-47 -> V (V^T out).
// Same per-block code as round-0's three gemm_bt launches; one dispatch removes two
// launch boundaries and x-major order packs 48 col-tiles per A-row-panel (fewer
// distinct A panels concurrent -> better L2 reuse).
__global__ __launch_bounds__(256)
void proj_all(const unsigned short* __restrict__ xb,
              const unsigned short* __restrict__ Wqb, const unsigned short* __restrict__ Wkb,
              const unsigned short* __restrict__ Wvb,
              const float* __restrict__ bq, const float* __restrict__ bk, const float* __restrict__ bvp,
              unsigned short* __restrict__ Qb, unsigned short* __restrict__ Kb,
              unsigned short* __restrict__ Vtb, float qscale) {
  __shared__ unsigned short As[128 * 64];  // 16 KB
  __shared__ unsigned short Bs[128 * 64];
  const int sel = blockIdx.x >> 4;
  const int n0 = (blockIdx.x & 15) * 128;
  const int m0 = blockIdx.y * 128;
  const int M = 2 * S_LEN, N = DMODEL, K = DMODEL;
  if (sel == 0)
    gemm128_body<0>(xb, Wqb, bq, Qb, M, N, K, qscale, m0, n0, As, Bs);
  else if (sel == 1)
    gemm128_body<0>(xb, Wkb, bk, Kb, M, N, K, 1.f, m0, n0, As, Bs);
  else
    gemm128_body<1>(xb, Wvb, bvp, Vtb, M, N, K, 1.f, m0, n0, As, Bs);
}

// output projection: grid (16, 32), fp32 out (round-0 exact)
__global__ __launch_bounds__(256)
void out128(const unsigned short* __restrict__ Ob, const unsigned short* __restrict__ Wob,
            const float* __restrict__ bo, float* __restrict__ out) {
  __shared__ unsigned short As[128 * 64];
  __shared__ unsigned short Bs[128 * 64];
  gemm128_body<2>(Ob, Wob, bo, out, 2 * S_LEN, DMODEL, DMODEL, 1.f,
                  blockIdx.y * 128, blockIdx.x * 128, As, Bs);
}

// ---------------- Flash attention (causal), BM=128, S^T orientation ----------------
// Round-0 exact (measured 79.7 us). Q,K: [b,s,h,hd] rows of [B*S, D]; Vt: [b,h,hd,s];
// O: [b,s,h,hd]. Q pre-scaled by log2(e)/sqrt(HD) so softmax uses exp2.
__global__ __launch_bounds__(256, 2)
void attn_fwd(const unsigned short* __restrict__ Qg, const unsigned short* __restrict__ Kg,
              const unsigned short* __restrict__ Vtg, unsigned short* __restrict__ Og) {
  __shared__ unsigned short Ks[2][64 * 128];  // 32 KB [buf][krow][chunk^(krow&15)]
  __shared__ unsigned short Vs[128 * 64];     // 16 KB [hd][chunk^(hd&7)]
  __shared__ unsigned short Ps[128 * 72];     // 18 KB [query][key], pitch 72 spreads banks

  const int t = threadIdx.x;
  const int lane = t & 63, w = t >> 6;
  const int quad = lane >> 4, lc = lane & 15;
  const int y = blockIdx.y;
  const int tile = (y < 16) ? (int)blockIdx.x : 15 - (int)blockIdx.x;
  const int b = y >> 4, h = y & 15;
  const size_t qkbase = (size_t)b * S_LEN * DMODEL + h * HDIM;
  const size_t vtbase = ((size_t)(b * DMODEL + h * HDIM)) * S_LEN;
  const int q0 = tile * 128;
  const int wrow = q0 + w * 32;  // wave's first q-row

  short8 aq[2][4];
#pragma unroll
  for (int pm = 0; pm < 2; pm++)
#pragma unroll
    for (int ks = 0; ks < 4; ks++)
      aq[pm][ks] = *(const short8*)&Qg[qkbase + (size_t)(wrow + pm * 16 + lc) * DMODEL + ks * 32 + quad * 8];

  const unsigned short* kga[4];
  const unsigned short* vga[4];
  int kloff[4], vloff[4];
#pragma unroll
  for (int i = 0; i < 4; i++) {
    int c = w * 4 + i;
    int krow = 4 * c + (lane >> 4);
    kga[i] = Kg + qkbase + (size_t)krow * DMODEL + ((lane & 15) ^ (krow & 15)) * 8;
    kloff[i] = c * 512 + lane * 8;
    int vrow = 8 * c + (lane >> 3);
    vga[i] = Vtg + vtbase + (size_t)vrow * S_LEN + ((lane & 7) ^ (vrow & 7)) * 8;
    vloff[i] = c * 512 + lane * 8;
  }

  floatx4 oaccT[8][2] = {};  // [hd tile mt8][pm]: O^T[hd=mt8*16+quad*4+r][query=pm*16+lc]
  float m_run[2] = {-1e30f, -1e30f}, l_run[2] = {0.f, 0.f};

  const int kiters = 2 * tile + 2;

  // prologue: K(0) into buf 0
#pragma unroll
  for (int i = 0; i < 4; i++) load_lds16(kga[i], &Ks[0][kloff[i]]);

  for (int kb = 0; kb < kiters; kb++) {
    const int k0 = kb * 64;
    const int cur = kb & 1;
    __syncthreads();  // drains K(kb) prefetch; fences PV(kb-1) reads of Vs

    // issue V(kb) (oldest 4) then K(kb+1) prefetch (clamped on last iter; 8 outstanding)
#pragma unroll
    for (int i = 0; i < 4; i++) load_lds16(vga[i] + k0, &Vs[vloff[i]]);
    {
      const size_t knext = (size_t)((kb + 1 < kiters) ? k0 + 64 : k0) * DMODEL;
#pragma unroll
      for (int i = 0; i < 4; i++) load_lds16(kga[i] + knext, &Ks[cur ^ 1][kloff[i]]);
    }

    const bool hasw = (k0 <= wrow + 31);  // wave has at least one unmasked column
    float alpha[2];
    if (hasw) {
      // ---- S^T = K Q^T : 64 keys x 32 queries ----
      floatx4 st[4][2];
#pragma unroll
      for (int mt = 0; mt < 4; mt++)
#pragma unroll
        for (int pm = 0; pm < 2; pm++) st[mt][pm] = (floatx4){0.f, 0.f, 0.f, 0.f};
#pragma unroll
      for (int ks = 0; ks < 4; ks++) {
        short8 kf[4];
#pragma unroll
        for (int mt = 0; mt < 4; mt++) {
          int n = mt * 16 + lc;
          kf[mt] = *(const short8*)&Ks[cur][n * 128 + (((ks * 4 + quad) ^ (n & 15)) * 8)];
        }
#pragma unroll
        for (int mt = 0; mt < 4; mt++)
#pragma unroll
          for (int pm = 0; pm < 2; pm++)
            st[mt][pm] = __builtin_amdgcn_mfma_f32_16x16x32_bf16(kf[mt], aq[pm][ks], st[mt][pm], 0, 0, 0);
      }

      // ---- causal mask + per-lane max over this lane's 16 keys ----
      float mx[2] = {-1e30f, -1e30f};
      if (k0 + 63 > wrow) {  // diagonal region: mask needed
#pragma unroll
        for (int pm = 0; pm < 2; pm++) {
          const int qq = wrow + pm * 16 + lc;
#pragma unroll
          for (int mt = 0; mt < 4; mt++) {
            const int key = k0 + mt * 16 + quad * 4;
#pragma unroll
            for (int r = 0; r < 4; r++) {
              if (key + r > qq) st[mt][pm][r] = -1e30f;
              mx[pm] = fmaxf(mx[pm], st[mt][pm][r]);
            }
          }
        }
      } else {
#pragma unroll
        for (int pm = 0; pm < 2; pm++)
#pragma unroll
          for (int mt = 0; mt < 4; mt++)
#pragma unroll
            for (int r = 0; r < 4; r++) mx[pm] = fmaxf(mx[pm], st[mt][pm][r]);
      }
      // row(=query) max: reduce across the 4 quads only (2 shuffles per pm)
#pragma unroll
      for (int pm = 0; pm < 2; pm++) {
        mx[pm] = fmaxf(mx[pm], __shfl_xor(mx[pm], 16));
        mx[pm] = fmaxf(mx[pm], __shfl_xor(mx[pm], 32));
        float mnew = fmaxf(m_run[pm], mx[pm]);
        alpha[pm] = __builtin_amdgcn_exp2f(m_run[pm] - mnew);
        m_run[pm] = mnew;
        l_run[pm] *= alpha[pm];
      }

      // ---- P = exp2(S^T - m): 4 consecutive keys per lane -> b64 writes; lane-partial sums ----
#pragma unroll
      for (int pm = 0; pm < 2; pm++)
#pragma unroll
        for (int mt = 0; mt < 4; mt++) {
          float p0 = __builtin_amdgcn_exp2f(st[mt][pm][0] - m_run[pm]);
          float p1 = __builtin_amdgcn_exp2f(st[mt][pm][1] - m_run[pm]);
          float p2 = __builtin_amdgcn_exp2f(st[mt][pm][2] - m_run[pm]);
          float p3 = __builtin_amdgcn_exp2f(st[mt][pm][3] - m_run[pm]);
          l_run[pm] += (p0 + p1) + (p2 + p3);
          ushort4 o;
          o.x = f2b(p0); o.y = f2b(p1); o.z = f2b(p2); o.w = f2b(p3);
          *(ushort4*)&Ps[(w * 32 + pm * 16 + lc) * 72 + mt * 16 + quad * 4] = o;
        }
    }

    // V(kb) landed (oldest 4 of 8); K(kb+1) prefetch stays in flight across this barrier.
    asm volatile("s_waitcnt vmcnt(4)\n\ts_barrier" ::: "memory");

    if (hasw) {
      // ---- rescale O^T ----
#pragma unroll
      for (int mt8 = 0; mt8 < 8; mt8++)
#pragma unroll
        for (int pm = 0; pm < 2; pm++) {
          oaccT[mt8][pm][0] *= alpha[pm]; oaccT[mt8][pm][1] *= alpha[pm];
          oaccT[mt8][pm][2] *= alpha[pm]; oaccT[mt8][pm][3] *= alpha[pm];
        }

      // ---- O^T += V^T P^T ----
#pragma unroll
      for (int ks = 0; ks < 2; ks++) {
        short8 pf[2];
#pragma unroll
        for (int pm = 0; pm < 2; pm++)
          pf[pm] = *(const short8*)&Ps[(w * 32 + pm * 16 + lc) * 72 + ks * 32 + quad * 8];
#pragma unroll
        for (int mt8 = 0; mt8 < 8; mt8++) {
          int n = mt8 * 16 + lc;
          short8 vf = *(const short8*)&Vs[n * 64 + (((ks * 4 + quad) ^ (n & 7)) * 8)];
#pragma unroll
          for (int pm = 0; pm < 2; pm++)
            oaccT[mt8][pm] = __builtin_amdgcn_mfma_f32_16x16x32_bf16(vf, pf[pm], oaccT[mt8][pm], 0, 0, 0);
        }
      }
    }
  }

  // final l reduce (2 shuffles), then O^T -> O write: 4 consecutive hd per lane = b64 store
#pragma unroll
  for (int pm = 0; pm < 2; pm++) {
    l_run[pm] += __shfl_xor(l_run[pm], 16);
    l_run[pm] += __shfl_xor(l_run[pm], 32);
    float inv = 1.f / l_run[pm];
    size_t obase = ((size_t)(b * S_LEN + wrow + pm * 16 + lc)) * DMODEL + h * HDIM;
#pragma unroll
    for (int mt8 = 0; mt8 < 8; mt8++) {
      ushort4 o;
      o.x = f2b(oaccT[mt8][pm][0] * inv);
      o.y = f2b(oaccT[mt8][pm][1] * inv);
      o.z = f2b(oaccT[mt8][pm][2] * inv);
      o.w = f2b(oaccT[mt8][pm][3] * inv);
      *(ushort4*)&Og[obase + mt8 * 16 + quad * 4] = o;
    }
  }
}

// ---------------- launch ----------------
extern "C" void kernel_launch(void* const* d_in, const int* in_sizes, int n_in,
                              void* d_out, int out_size, void* d_ws, size_t ws_size,
                              hipStream_t stream) {
  const float* x  = (const float*)d_in[0];
  const float* Wq = (const float*)d_in[1];
  const float* bq = (const float*)d_in[2];
  const float* Wk = (const float*)d_in[3];
  const float* bk = (const float*)d_in[4];
  const float* Wv = (const float*)d_in[5];
  const float* bv = (const float*)d_in[6];
  const float* Wo = (const float*)d_in[7];
  const float* bo = (const float*)d_in[8];

  char* w = (char*)d_ws;  // needs 112 MB
  unsigned short* xb  = (unsigned short*)(w);
  unsigned short* Wqb = (unsigned short*)(w + (size_t)16 * (1 << 20));
  unsigned short* Wkb = (unsigned short*)(w + (size_t)24 * (1 << 20));
  unsigned short* Wvb = (unsigned short*)(w + (size_t)32 * (1 << 20));
  unsigned short* Wob = (unsigned short*)(w + (size_t)40 * (1 << 20));
  unsigned short* Qb  = (unsigned short*)(w + (size_t)48 * (1 << 20));
  unsigned short* Kb  = (unsigned short*)(w + (size_t)64 * (1 << 20));
  unsigned short* Vtb = (unsigned short*)(w + (size_t)80 * (1 << 20));
  unsigned short* Ob  = (unsigned short*)(w + (size_t)96 * (1 << 20));

  cvt_all<<<dim3(4096, 6), 256, 0, stream>>>(x, Wq, Wk, Wv, Wo, xb, Wqb, Wkb, Wvb, Wob);

  // Q scale: log2(e)/sqrt(128) so attention softmax can use exp2 directly
  const float qscale = 0.08838834764831843f * 1.4426950408889634f;
  proj_all<<<dim3(48, 32), 256, 0, stream>>>(xb, Wqb, Wkb, Wvb, bq, bk, bv, Qb, Kb, Vtb, qscale);

  attn_fwd<<<dim3(16, 32), 256, 0, stream>>>(Qb, Kb, Vtb, Ob);

  out128<<<dim3(16, 32), 256, 0, stream>>>(Ob, Wob, bo, (float*)d_out);
}